// Round 9
// baseline (1129.019 us; speedup 1.0000x reference)
//
#include <hip/hip_runtime.h>
#include <math.h>

namespace {

constexpr int C_ = 3, T_ = 3000, F_ = 103, NB_ = 6;
constexpr int TCH = 125, TPB = 128;          // 125 t per 128-thread block; 24*64=1536 blocks
constexpr int BS_[NB_]  = {1, 10, 20, 30, 40, 61};
constexpr int BNB_[NB_] = {10, 11, 11, 11, 22, 16};
constexpr int BP_[NB_]  = {12, 12, 12, 12, 24, 16};       // padded to x4 (zero-padded weights)
constexpr int WOFP_[NB_] = {0, 216, 432, 648, 864, 1296}; // cumsum 18*BP
constexpr int WTOTP = 1584;
constexpr int PLANE = T_ * F_;

// param LDS offsets
constexpr int OAW = 0, OAB = 54, OF1 = 72, OF1B = 180, OF2 = 186, OF2B = 294,
              OBG = 312, OGW = 318, OGB = 327, OPW = 330, OPB = 339, PTOT = 342;

typedef float f4v __attribute__((ext_vector_type(4), aligned(4)));

__device__ __forceinline__ float softplus_full_(float x) {
  return fmaxf(x, 0.0f) + log1pf(expf(-fabsf(x)));
}
__device__ __forceinline__ float sigmoid_(float z) {
  return 1.0f / (1.0f + __expf(-z));
}
__device__ __forceinline__ float gelu_(float x) {
  return x * sigmoid_(1.595769122f * x * (1.0f + 0.044715f * x * x));
}

// ---- pre-kernel: padded gaussian bank + folded proj/BN -> d_ws ----------------
__global__ __launch_bounds__(128)
void prep_kernel(const float* __restrict__ centers,
                 const float* __restrict__ widths,
                 const float* __restrict__ gains,
                 const float* __restrict__ proj_w,
                 const float* __restrict__ proj_b,
                 const float* __restrict__ bn_gamma,
                 const float* __restrict__ bn_beta,
                 const float* __restrict__ bn_mean,
                 const float* __restrict__ bn_var,
                 float* __restrict__ ws)
{
  const int q = threadIdx.x;
  if (q < 108) {
    int i = q / 18;
    int p = q - i * 18;                       // c*6+n
    int s = BS_[i], nb = BNB_[i];
    float mu = softplus_full_(centers[q]) + (float)s;
    mu = fminf(fmaxf(mu, (float)s), (float)(s + nb - 1));
    float sd = softplus_full_(widths[q]) + 0.001f;
    sd = fminf(fmaxf(sd, 0.5f), 2.0f * (float)nb / 6.0f);
    float sum = 0.0f;
    for (int f = 0; f < nb; ++f) {
      float d = ((float)f - mu) / sd;
      sum += __expf(-0.5f * d * d);
    }
    float sc = gains[q] / (sum + 1e-6f);
    float* wrow = &ws[WOFP_[i] + p * BP_[i]];
    for (int f = 0; f < nb; ++f) {
      float d = ((float)f - mu) / sd;
      wrow[f] = sc * __expf(-0.5f * d * d);
    }
    for (int f = nb; f < BP_[i]; ++f) wrow[f] = 0.0f;     // zero pads
  } else if (q < 117) {
    int k = q - 108, d = k / 3;
    float sc = bn_gamma[d] / sqrtf(bn_var[d] + 1e-5f);
    ws[WTOTP + k] = proj_w[k] * sc;
  } else if (q < 120) {
    int d = q - 117;
    float sc = bn_gamma[d] / sqrtf(bn_var[d] + 1e-5f);
    ws[WTOTP + 9 + d] = (proj_b[d] - bn_mean[d]) * sc + bn_beta[d];
  }
}

// ---- main kernel: one thread per (b,t) ----------------------------------------
__global__ __launch_bounds__(TPB)
void sleepband_kernel(const float* __restrict__ spec,
                      const float* __restrict__ ws,
                      const float* __restrict__ align_w,
                      const float* __restrict__ align_b,
                      const float* __restrict__ fc1_w,
                      const float* __restrict__ fc1_b,
                      const float* __restrict__ fc2_w,
                      const float* __restrict__ fc2_b,
                      const float* __restrict__ band_gain,
                      const float* __restrict__ gate_w,
                      const float* __restrict__ gate_b,
                      float* __restrict__ out)
{
  __shared__ __align__(16) float sW[WTOTP];   // gaussian weights (broadcast reads)
  __shared__ float sP[PTOT];                  // small params (broadcast reads)

  const int tid = threadIdx.x;
  for (int k = tid; k < WTOTP; k += TPB) sW[k] = ws[k];
  if (tid < 54)  sP[OAW + tid] = align_w[tid];
  if (tid < 18)  sP[OAB + tid] = align_b[tid];
  if (tid < 108) sP[OF1 + tid] = fc1_w[tid];
  if (tid < 6)   sP[OF1B + tid] = fc1_b[tid];
  if (tid < 108) sP[OF2 + tid] = fc2_w[tid];
  if (tid < 18)  sP[OF2B + tid] = fc2_b[tid];
  if (tid < 6)   sP[OBG + tid] = band_gain[tid];
  if (tid < 9)   sP[OGW + tid] = gate_w[tid];
  if (tid < 3)   sP[OGB + tid] = gate_b[tid];
  if (tid < 12)  sP[OPW + tid] = ws[WTOTP + tid];   // folded proj w(9) + b(3)
  __syncthreads();                                  // the only barrier

  const int b  = blockIdx.y;
  const int t0 = blockIdx.x * TCH;
  const int tl = (tid < TCH) ? tid : (TCH - 1);     // clamp: lanes 125..127 redo t=124
  const bool valid = tid < TCH;
  const int t = t0 + tl;

  const float* r0 = spec + ((size_t)b * 3 + 0) * PLANE + (size_t)t * F_;
  const float* r1 = r0 + PLANE;
  const float* r2 = r1 + PLANE;

  // ---------------- Phase A: filt[i][c][n], all-register -----------------------
  float filt[6][3][6];
  #pragma unroll
  for (int i = 0; i < NB_; ++i) {
    #pragma unroll
    for (int c = 0; c < 3; ++c)
      #pragma unroll
      for (int n = 0; n < 6; ++n) filt[i][c][n] = 0.0f;
    #pragma unroll
    for (int k = 0; k < BP_[i] / 4; ++k) {
      const int f0 = BS_[i] + 4 * k;
      const f4v s0 = *(const f4v*)(r0 + f0);
      const f4v s1 = *(const f4v*)(r1 + f0);
      const f4v s2 = *(const f4v*)(r2 + f0);
      #pragma unroll
      for (int c = 0; c < 3; ++c) {
        const f4v sc = (c == 0) ? s0 : ((c == 1) ? s1 : s2);
        #pragma unroll
        for (int n = 0; n < 6; ++n) {
          const f4v w = *(const f4v*)&sW[WOFP_[i] + (c * 6 + n) * BP_[i] + 4 * k];
          float a = filt[i][c][n];
          a += sc.x * w.x; a += sc.y * w.y; a += sc.z * w.z; a += sc.w * w.w;
          filt[i][c][n] = a;
        }
      }
    }
  }

  // ---------------- align + MLP + softmax + scale, per n, all-register ---------
  #pragma unroll
  for (int n = 0; n < 6; ++n) {
    float al[18];
    #pragma unroll
    for (int i = 0; i < 6; ++i)
      #pragma unroll
      for (int d = 0; d < 3; ++d)
        al[i * 3 + d] = sP[OAW + i * 9 + d * 3 + 0] * filt[i][0][n]
                      + sP[OAW + i * 9 + d * 3 + 1] * filt[i][1][n]
                      + sP[OAW + i * 9 + d * 3 + 2] * filt[i][2][n]
                      + sP[OAB + i * 3 + d];
    float h[6];
    #pragma unroll
    for (int o = 0; o < 6; ++o) {
      float a = sP[OF1B + o];
      #pragma unroll
      for (int k = 0; k < 18; ++k) a += sP[OF1 + o * 18 + k] * al[k];
      h[o] = gelu_(a);
    }
    #pragma unroll
    for (int c = 0; c < 3; ++c) {
      float a[6];
      #pragma unroll
      for (int i = 0; i < 6; ++i) {
        float x = sP[OF2B + i * 3 + c];
        #pragma unroll
        for (int o = 0; o < 6; ++o) x += sP[OF2 + (i * 3 + c) * 6 + o] * h[o];
        a[i] = x;
      }
      float m = a[0];
      #pragma unroll
      for (int i = 1; i < 6; ++i) m = fmaxf(m, a[i]);
      float e[6], ssum = 0.0f;
      #pragma unroll
      for (int i = 0; i < 6; ++i) { e[i] = __expf(a[i] - m); ssum += e[i]; }
      const float inv = 1.0f / ssum;
      #pragma unroll
      for (int i = 0; i < 6; ++i)
        filt[i][c][n] = al[i * 3 + c] * (e[i] * inv) * sP[OBG + i];   // overwrite w/ scaled
    }
  }

  // ---------------- Final: unrolled 103-bin upsample + gate + proj + gelu ------
  float gw[9], pw[9], gb3[3], pb3[3];
  #pragma unroll
  for (int k = 0; k < 9; ++k) { gw[k] = sP[OGW + k]; pw[k] = sP[OPW + k]; }
  #pragma unroll
  for (int k = 0; k < 3; ++k) { gb3[k] = sP[OGB + k]; pb3[k] = sP[OPB + k]; }

  float* o0 = out + ((size_t)b * 3 + 0) * PLANE + (size_t)t * F_;
  float* o1 = o0 + PLANE;
  float* o2 = o1 + PLANE;

  #pragma unroll
  for (int q = 0; q < 26; ++q) {                     // 25 full float4 chunks + tail
    const int fb = 4 * q;
    if (fb >= F_) break;
    const bool full = (fb + 4 <= F_);
    f4v s0, s1, s2;
    if (full) {
      s0 = *(const f4v*)(r0 + fb); s1 = *(const f4v*)(r1 + fb); s2 = *(const f4v*)(r2 + fb);
    } else {
      s0 = (f4v){r0[100], r0[101], r0[102], 0.f};
      s1 = (f4v){r1[100], r1[101], r1[102], 0.f};
      s2 = (f4v){r2[100], r2[101], r2[102], 0.f};
    }
    f4v w0v, w1v, w2v;
    #pragma unroll
    for (int jj = 0; jj < 4; ++jj) {
      const int F = fb + jj;
      if (F >= F_) { w0v[jj] = 0.f; w1v[jj] = 0.f; w2v[jj] = 0.f; continue; }
      float e0 = 0.f, e1 = 0.f, e2 = 0.f;
      #pragma unroll
      for (int i = 0; i < NB_; ++i) {
        if (F >= BS_[i] && F < BS_[i] + BNB_[i]) {   // compile-time prunable
          const int j = F - BS_[i];
          float src = ((float)j + 0.5f) * 6.0f / (float)BNB_[i] - 0.5f;
          src = src > 0.0f ? src : 0.0f;
          const int x0 = (int)src;
          const int x1 = (x0 < 5) ? x0 + 1 : 5;
          const float wl = src - (float)x0;
          const float om = 1.0f - wl;
          e0 += filt[i][0][x0] * om + filt[i][0][x1] * wl;
          e1 += filt[i][1][x0] * om + filt[i][1][x1] * wl;
          e2 += filt[i][2][x0] * om + filt[i][2][x1] * wl;
        }
      }
      const float sv0 = s0[jj], sv1 = s1[jj], sv2 = s2[jj];
      const float rr0 = e0 - sv0, rr1 = e1 - sv1, rr2 = e2 - sv2;
      const float e20 = sv0 + sigmoid_(gw[0]*rr0 + gw[1]*rr1 + gw[2]*rr2 + gb3[0]) * rr0;
      const float e21 = sv1 + sigmoid_(gw[3]*rr0 + gw[4]*rr1 + gw[5]*rr2 + gb3[1]) * rr1;
      const float e22 = sv2 + sigmoid_(gw[6]*rr0 + gw[7]*rr1 + gw[8]*rr2 + gb3[2]) * rr2;
      w0v[jj] = gelu_(pw[0]*e20 + pw[1]*e21 + pw[2]*e22 + pb3[0]);
      w1v[jj] = gelu_(pw[3]*e20 + pw[4]*e21 + pw[5]*e22 + pb3[1]);
      w2v[jj] = gelu_(pw[6]*e20 + pw[7]*e21 + pw[8]*e22 + pb3[2]);
    }
    if (valid) {
      if (full) {
        *(f4v*)(o0 + fb) = w0v; *(f4v*)(o1 + fb) = w1v; *(f4v*)(o2 + fb) = w2v;
      } else {
        o0[100] = w0v[0]; o0[101] = w0v[1]; o0[102] = w0v[2];
        o1[100] = w1v[0]; o1[101] = w1v[1]; o1[102] = w1v[2];
        o2[100] = w2v[0]; o2[101] = w2v[1]; o2[102] = w2v[2];
      }
    }
  }
}

} // namespace

extern "C" void kernel_launch(void* const* d_in, const int* in_sizes, int n_in,
                              void* d_out, int out_size, void* d_ws, size_t ws_size,
                              hipStream_t stream) {
  (void)n_in; (void)out_size; (void)ws_size;
  const int B = in_sizes[0] / (C_ * T_ * F_);   // 64
  float* ws = (float*)d_ws;                     // 1596 floats used
  prep_kernel<<<1, 128, 0, stream>>>(
      (const float*)d_in[1],  (const float*)d_in[2],  (const float*)d_in[3],
      (const float*)d_in[13], (const float*)d_in[14], (const float*)d_in[15],
      (const float*)d_in[16], (const float*)d_in[17], (const float*)d_in[18], ws);
  dim3 grid(T_ / TCH, B);                       // (24, 64) = 1536 blocks
  sleepband_kernel<<<grid, TPB, 0, stream>>>(
      (const float*)d_in[0],  ws,
      (const float*)d_in[4],  (const float*)d_in[5],
      (const float*)d_in[6],  (const float*)d_in[7],  (const float*)d_in[8],
      (const float*)d_in[9],  (const float*)d_in[10], (const float*)d_in[11],
      (const float*)d_in[12], (float*)d_out);
}

// Round 10
// 239.123 us; speedup vs baseline: 4.7215x; 4.7215x over previous
//
#include <hip/hip_runtime.h>
#include <math.h>

namespace {

constexpr int C_ = 3, T_ = 3000, F_ = 103, NB_ = 6;
constexpr int TT = 20;                       // t-steps per tile
constexpr int NT = 5;                        // tiles per block; 3000/(20*5)=30 chunks
constexpr int BS[NB_]  = {1, 10, 20, 30, 40, 61};
constexpr int BNB[NB_] = {10, 11, 11, 11, 22, 16};
constexpr int BOF[NB_] = {0, 10, 21, 32, 43, 65};   // cumsum, total 81
constexpr int SPF = 81;                      // staged spec cols (bands span f=1..76)
constexpr int PLANE = T_ * F_;               // 309000
constexpr int SECP = 2064;                   // enh plane stride (2060 padded to x4)
constexpr int WTOT = 1458;                   // gaussian weights (R3 layout)
constexpr int POOL2 = 6192;                  // max(4860, 3*2064)

__device__ __forceinline__ float softplus_(float x) {
  return fmaxf(x, 0.0f) + log1pf(expf(-fabsf(x)));
}
__device__ __forceinline__ float sigmoid_(float z) {
  return 1.0f / (1.0f + __expf(-z));
}
__device__ __forceinline__ float gelu_(float x) {
  return x * sigmoid_(1.595769122f * x * (1.0f + 0.044715f * x * x));
}

// ---- pre-kernel: gaussian bank (R3 layout) + folded proj/BN -> d_ws -----------
// ws floats: [0..1457] weights at BOF[i]*18 + p*nb + f ; [1458..1466] projW ; [1467..1469] projB
__global__ __launch_bounds__(128)
void prep_kernel(const float* __restrict__ centers,
                 const float* __restrict__ widths,
                 const float* __restrict__ gains,
                 const float* __restrict__ proj_w,
                 const float* __restrict__ proj_b,
                 const float* __restrict__ bn_gamma,
                 const float* __restrict__ bn_beta,
                 const float* __restrict__ bn_mean,
                 const float* __restrict__ bn_var,
                 float* __restrict__ ws)
{
  const int q = threadIdx.x;
  if (q < 108) {
    int i = q / 18;
    int p = q - i * 18;
    int s = BS[i], nb = BNB[i];
    float mu = softplus_(centers[q]) + (float)s;
    mu = fminf(fmaxf(mu, (float)s), (float)(s + nb - 1));
    float sd = softplus_(widths[q]) + 0.001f;
    sd = fminf(fmaxf(sd, 0.5f), 2.0f * (float)nb / 6.0f);
    float sum = 0.0f;
    for (int f = 0; f < nb; ++f) {
      float d = ((float)f - mu) / sd;
      sum += __expf(-0.5f * d * d);
    }
    float sc = gains[q] / (sum + 1e-6f);
    float* wrow = &ws[BOF[i] * 18 + p * nb];
    for (int f = 0; f < nb; ++f) {
      float d = ((float)f - mu) / sd;
      wrow[f] = sc * __expf(-0.5f * d * d);
    }
  } else if (q < 117) {
    int k = q - 108, d = k / 3;
    float sc = bn_gamma[d] / sqrtf(bn_var[d] + 1e-5f);
    ws[WTOT + k] = proj_w[k] * sc;
  } else if (q < 120) {
    int d = q - 117;
    float sc = bn_gamma[d] / sqrtf(bn_var[d] + 1e-5f);
    ws[WTOT + 9 + d] = (proj_b[d] - bn_mean[d]) * sc + bn_beta[d];
  }
}

// ---- main kernel: R3 phase structure, persistent over NT tiles ----------------
__global__ __launch_bounds__(256)
void sleepband_kernel(const float* __restrict__ spec,
                      const float* __restrict__ ws,
                      const float* __restrict__ align_w,
                      const float* __restrict__ align_b,
                      const float* __restrict__ fc1_w,
                      const float* __restrict__ fc1_b,
                      const float* __restrict__ fc2_w,
                      const float* __restrict__ fc2_b,
                      const float* __restrict__ band_gain,
                      const float* __restrict__ gate_w,
                      const float* __restrict__ gate_b,
                      float* __restrict__ out)
{
  // pool: [stage/A] spec[C][TT][81] (4860)  ||  [B2/final] enh[3][SECP] (6192)
  __shared__ __align__(16) float sPool[POOL2];
  __shared__ float sW[WTOT];             // persistent across tiles
  __shared__ float sBand[TT][109];       // odd stride -> conflict-free
  __shared__ float sAw[54], sAb[18], sF1[108], sF1b[6], sF2[108], sF2b[18],
                   sBg[6], sGw[9], sGb[3], sPw[9], sPb[3];

  const int tid = threadIdx.x;
  const int b   = blockIdx.y;
  const float* specB = spec + (size_t)b * C_ * PLANE;
  float* outBase = out + (size_t)b * C_ * PLANE;

  // ---- one-time prologue: params + gaussian weights from d_ws ----
  for (int k = tid; k < WTOT; k += 256) sW[k] = ws[k];
  if (tid < 54)  sAw[tid]  = align_w[tid];
  if (tid < 18)  sAb[tid]  = align_b[tid];
  if (tid < 108) sF1[tid]  = fc1_w[tid];
  if (tid < 6)   sF1b[tid] = fc1_b[tid];
  if (tid < 108) sF2[tid]  = fc2_w[tid];
  if (tid < 18)  sF2b[tid] = fc2_b[tid];
  if (tid < 6)   sBg[tid]  = band_gain[tid];
  if (tid < 9)   sGw[tid]  = gate_w[tid];
  if (tid < 3)   sGb[tid]  = gate_b[tid];
  if (tid < 9)   sPw[tid]  = ws[WTOT + tid];
  if (tid < 3)   sPb[tid]  = ws[WTOT + 9 + tid];

  for (int tile = 0; tile < NT; ++tile) {
    const int t0 = (blockIdx.x * NT + tile) * TT;

    // ---- stage spec band region (coalesced); pool free: enh readers sync'd ----
    for (int li = tid; li < C_ * TT * SPF; li += 256) {
      int c   = li / (TT * SPF);
      int rem = li - c * (TT * SPF);
      int tt  = rem / SPF;
      int f   = rem - tt * SPF;
      sPool[li] = specB[(size_t)c * PLANE + (size_t)(t0 + tt) * F_ + f];
    }
    __syncthreads();

    // ---- Phase A: filt (18*TT=360 tasks) ----
    for (int task = tid; task < 18 * TT; task += 256) {
      int p  = task / TT;
      int tt = task - p * TT;
      int c  = p / 6;
      int n  = p - c * 6;
      const float* srowb = &sPool[(c * TT + tt) * SPF];
      #pragma unroll
      for (int i = 0; i < NB_; ++i) {
        const float* wrow = &sW[BOF[i] * 18 + p * BNB[i]];
        const float* srow = srowb + BS[i];
        float acc = 0.0f;
        #pragma unroll
        for (int f = 0; f < BNB[i]; ++f) acc += srow[f] * wrow[f];
        sBand[tt][(i * 3 + c) * 6 + n] = acc;
      }
    }
    __syncthreads();

    // ---- Phase B: align + MLP + softmax + scale (6*TT tasks) ----
    if (tid < 6 * TT) {
      int n  = tid / TT;
      int tt = tid - n * TT;
      float al[18];
      #pragma unroll
      for (int i = 0; i < 6; ++i) {
        float f0 = sBand[tt][(i * 3 + 0) * 6 + n];
        float f1 = sBand[tt][(i * 3 + 1) * 6 + n];
        float f2 = sBand[tt][(i * 3 + 2) * 6 + n];
        #pragma unroll
        for (int d = 0; d < 3; ++d)
          al[i * 3 + d] = sAw[i * 9 + d * 3 + 0] * f0 + sAw[i * 9 + d * 3 + 1] * f1 +
                          sAw[i * 9 + d * 3 + 2] * f2 + sAb[i * 3 + d];
      }
      float h[6];
      #pragma unroll
      for (int o = 0; o < 6; ++o) {
        float acc = sF1b[o];
        #pragma unroll
        for (int k = 0; k < 18; ++k) acc += sF1[o * 18 + k] * al[k];
        h[o] = gelu_(acc);
      }
      float at[18];
      #pragma unroll
      for (int k = 0; k < 18; ++k) {
        float acc = sF2b[k];
        #pragma unroll
        for (int o = 0; o < 6; ++o) acc += sF2[k * 6 + o] * h[o];
        at[k] = acc;
      }
      #pragma unroll
      for (int c = 0; c < 3; ++c) {
        float m = at[c];
        #pragma unroll
        for (int i = 1; i < 6; ++i) m = fmaxf(m, at[i * 3 + c]);
        float e[6], ssum = 0.0f;
        #pragma unroll
        for (int i = 0; i < 6; ++i) { e[i] = __expf(at[i * 3 + c] - m); ssum += e[i]; }
        float inv = 1.0f / ssum;
        #pragma unroll
        for (int i = 0; i < 6; ++i)
          sBand[tt][(i * 3 + c) * 6 + n] = al[i * 3 + c] * (e[i] * inv) * sBg[i];
      }
    }
    __syncthreads();

    // ---- Phase B2: compile-time-tap upsample into dense enh ----
    if (tid < C_ * TT) {
      const int c  = tid / TT;
      const int tt = tid - c * TT;
      float bnd[36];
      #pragma unroll
      for (int i = 0; i < 6; ++i)
        #pragma unroll
        for (int n = 0; n < 6; ++n)
          bnd[i * 6 + n] = sBand[tt][(i * 3 + c) * 6 + n];
      float* row = &sPool[c * SECP + tt * F_];
      row[0] = 0.0f;
      float carry = 0.0f;
      #pragma unroll
      for (int i = 0; i < NB_; ++i) {
        #pragma unroll
        for (int j = 0; j < BNB[i]; ++j) {
          float src = ((float)j + 0.5f) * 6.0f / (float)BNB[i] - 0.5f;
          src = src > 0.0f ? src : 0.0f;
          int   x0 = (int)src;
          int   x1 = (x0 < 5) ? x0 + 1 : 5;
          float wl = src - (float)x0;
          float v  = bnd[i * 6 + x0] * (1.0f - wl) + bnd[i * 6 + x1] * wl;
          if (j == 0) v += carry;
          if (i < NB_ - 1 && j == BNB[i] - 1) carry = v;
          else row[BS[i] + j] = v;
        }
      }
      #pragma unroll
      for (int f = 77; f < F_; ++f) row[f] = 0.0f;
    }
    __syncthreads();

    // ---- Final: flat float4 gate + folded proj + gelu ----
    float gw[9], pw[9], gb3[3], pb3[3];
    #pragma unroll
    for (int k = 0; k < 9; ++k) { gw[k] = sGw[k]; pw[k] = sPw[k]; }
    #pragma unroll
    for (int k = 0; k < 3; ++k) { gb3[k] = sGb[k]; pb3[k] = sPb[k]; }

    const float* sp0 = specB + (size_t)t0 * F_;
    float* outB = outBase + (size_t)t0 * F_;
    for (int e4 = tid; e4 < (TT * F_) / 4; e4 += 256) {
      const int e = e4 * 4;
      const float4 sA = *(const float4*)(sp0 + e);
      const float4 sB = *(const float4*)(sp0 + PLANE + e);
      const float4 sC = *(const float4*)(sp0 + 2 * PLANE + e);
      const float4 eA = *(const float4*)&sPool[0 * SECP + e];
      const float4 eB = *(const float4*)&sPool[1 * SECP + e];
      const float4 eC = *(const float4*)&sPool[2 * SECP + e];
      float4 oA, oB, oC;
      const float* sAp = (const float*)&sA; const float* sBp = (const float*)&sB;
      const float* sCp = (const float*)&sC;
      const float* eAp = (const float*)&eA; const float* eBp = (const float*)&eB;
      const float* eCp = (const float*)&eC;
      float* oAp = (float*)&oA; float* oBp = (float*)&oB; float* oCp = (float*)&oC;
      #pragma unroll
      for (int j = 0; j < 4; ++j) {
        float sv0 = sAp[j], sv1 = sBp[j], sv2 = sCp[j];
        float r0 = eAp[j] - sv0, r1 = eBp[j] - sv1, r2 = eCp[j] - sv2;
        float e20 = sv0 + sigmoid_(gw[0] * r0 + gw[1] * r1 + gw[2] * r2 + gb3[0]) * r0;
        float e21 = sv1 + sigmoid_(gw[3] * r0 + gw[4] * r1 + gw[5] * r2 + gb3[1]) * r1;
        float e22 = sv2 + sigmoid_(gw[6] * r0 + gw[7] * r1 + gw[8] * r2 + gb3[2]) * r2;
        float y0 = pw[0] * e20 + pw[1] * e21 + pw[2] * e22 + pb3[0];
        float y1 = pw[3] * e20 + pw[4] * e21 + pw[5] * e22 + pb3[1];
        float y2 = pw[6] * e20 + pw[7] * e21 + pw[8] * e22 + pb3[2];
        oAp[j] = gelu_(y0); oBp[j] = gelu_(y1); oCp[j] = gelu_(y2);
      }
      *(float4*)(outB + e) = oA;
      *(float4*)(outB + PLANE + e) = oB;
      *(float4*)(outB + 2 * PLANE + e) = oC;
    }
    __syncthreads();   // protect sPool (enh) before next tile's staging
  }
}

} // namespace

extern "C" void kernel_launch(void* const* d_in, const int* in_sizes, int n_in,
                              void* d_out, int out_size, void* d_ws, size_t ws_size,
                              hipStream_t stream) {
  (void)n_in; (void)out_size; (void)ws_size;
  const int B = in_sizes[0] / (C_ * T_ * F_);   // 64
  float* ws = (float*)d_ws;                     // 1470 floats used
  prep_kernel<<<1, 128, 0, stream>>>(
      (const float*)d_in[1],  (const float*)d_in[2],  (const float*)d_in[3],
      (const float*)d_in[13], (const float*)d_in[14], (const float*)d_in[15],
      (const float*)d_in[16], (const float*)d_in[17], (const float*)d_in[18], ws);
  dim3 grid(T_ / (TT * NT), B);                 // (30, 64)
  sleepband_kernel<<<grid, 256, 0, stream>>>(
      (const float*)d_in[0],  ws,
      (const float*)d_in[4],  (const float*)d_in[5],
      (const float*)d_in[6],  (const float*)d_in[7],  (const float*)d_in[8],
      (const float*)d_in[9],  (const float*)d_in[10], (const float*)d_in[11],
      (const float*)d_in[12], (float*)d_out);
}